// Round 3
// baseline (535.249 us; speedup 1.0000x reference)
//
#include <hip/hip_runtime.h>
#include <math.h>

// Problem shape (fixed by setup_inputs)
constexpr int Bn = 8, Dn = 64, Hn = 256, Wn = 512;
constexpr int HW   = Hn * Wn;            // 131072
constexpr int NPIX = Bn * HW;            // 1048576
constexpr int TPB  = 256;                // 4 waves
constexpr int PXB  = 256;                // pixels per block (64 lanes x float4)
constexpr int NBLK = NPIX / PXB;         // 4096
constexpr int DPW  = Dn / 4;             // 16 d-planes per wave

typedef float fx4 __attribute__((ext_vector_type(4)));

// entropy(p) = log(sum_d exp(sim_d)) - (sum_d T_d*sim_d)/(sum_d T_d),
// T_d = exp(-|g-2d|) = min( e^{g-2d0} * e^{-2i},  e^{2d0-g} * e^{2i} ),  d=d0+i.
// e^{+-2i} are compile-time literals; only 2 exps per pixel per wave.
// g=inf (unknown): Pa=inf, Pb=0 -> t=min(inf,0)=0; pixel excluded via isfinite.
__global__ __launch_bounds__(TPB) void sce_main(const float* __restrict__ sim,
                                                const float* __restrict__ gt,
                                                float* __restrict__ accf,
                                                unsigned* __restrict__ ticket,
                                                float* __restrict__ out) {
    const int lane = threadIdx.x & 63;
    const int wave = threadIdx.x >> 6;
    const int p0   = blockIdx.x * PXB + lane * 4;   // chunk never crosses a batch image
    const int b    = p0 / HW;
    const int rem  = p0 - b * HW;
    const float* base = sim + (size_t)b * Dn * HW + rem;
    const int d0 = wave * DPW;

    const fx4 g4 = *reinterpret_cast<const fx4*>(gt + p0);  // cached: 4 waves share
    float gg[4] = {g4.x, g4.y, g4.z, g4.w};

    float Pa[4], Pb[4];
#pragma unroll
    for (int j = 0; j < 4; ++j) {
        Pa[j] = __expf(gg[j] - 2.0f * (float)d0);   // e^{g-2d0} (inf ok)
        Pb[j] = __expf(2.0f * (float)d0 - gg[j]);   // e^{2d0-g} (0 ok)
    }

    // Issue all 16 plane loads before any compute (16 KB/wave in flight).
    fx4 v0[8], v1[8];
#pragma unroll
    for (int i = 0; i < 8; ++i)
        v0[i] = __builtin_nontemporal_load(
            reinterpret_cast<const fx4*>(base + (size_t)(d0 + i) * HW));
#pragma unroll
    for (int i = 0; i < 8; ++i)
        v1[i] = __builtin_nontemporal_load(
            reinterpret_cast<const fx4*>(base + (size_t)(d0 + 8 + i) * HW));

    float s[4]  = {0.f, 0.f, 0.f, 0.f};
    float S1[4] = {0.f, 0.f, 0.f, 0.f};
    float S2[4] = {0.f, 0.f, 0.f, 0.f};

#pragma unroll
    for (int i = 0; i < DPW; ++i) {
        const fx4 vv = (i < 8) ? v0[i & 7] : v1[i & 7];
        const float ra = __builtin_expf(-2.0f * (float)i);  // folded literal
        const float rb = __builtin_expf( 2.0f * (float)i);  // folded literal
        float v[4] = {vv.x, vv.y, vv.z, vv.w};
#pragma unroll
        for (int j = 0; j < 4; ++j) {
            s[j] += __expf(v[j]);
            float t = fminf(Pa[j] * ra, Pb[j] * rb);        // exp(-|g-2d|)
            S1[j] += t;
            S2[j] = fmaf(t, v[j], S2[j]);
        }
    }

    // Cross-wave combine: s,S1,S2 are additive over d. Lane-major -> no conflicts.
    __shared__ float red[4][12][64];
#pragma unroll
    for (int j = 0; j < 4; ++j) {
        red[wave][j][lane]     = s[j];
        red[wave][4 + j][lane] = S1[j];
        red[wave][8 + j][lane] = S2[j];
    }
    __syncthreads();

    if (wave == 0) {
        float lsum = 0.f, lcnt = 0.f;
#pragma unroll
        for (int j = 0; j < 4; ++j) {
            float st = red[0][j][lane] + red[1][j][lane] + red[2][j][lane] + red[3][j][lane];
            float s1 = red[0][4+j][lane] + red[1][4+j][lane] + red[2][4+j][lane] + red[3][4+j][lane];
            float s2 = red[0][8+j][lane] + red[1][8+j][lane] + red[2][8+j][lane] + red[3][8+j][lane];
            if (isfinite(gg[j])) {
                lsum += __logf(st) - s2 / s1;
                lcnt += 1.0f;
            }
        }
#pragma unroll
        for (int off = 32; off > 0; off >>= 1) {
            lsum += __shfl_down(lsum, off, 64);
            lcnt += __shfl_down(lcnt, off, 64);
        }
        if (lane == 0) {
            atomicAdd(&accf[0], lsum);
            atomicAdd(&accf[1], lcnt);
            __threadfence();
            unsigned old = atomicAdd(ticket, 1u);
            if (old == NBLK - 1) {                 // last block finalizes
                __threadfence();
                float ts = atomicAdd(&accf[0], 0.0f);
                float tc = atomicAdd(&accf[1], 0.0f);
                out[0] = ts / tc;
            }
        }
    }
}

extern "C" void kernel_launch(void* const* d_in, const int* in_sizes, int n_in,
                              void* d_out, int out_size, void* d_ws, size_t ws_size,
                              hipStream_t stream) {
    const float* sim = (const float*)d_in[0];
    const float* gt  = (const float*)d_in[1];
    float* accf = (float*)d_ws;                  // [sum, cnt]
    unsigned* ticket = (unsigned*)d_ws + 2;
    hipMemsetAsync(d_ws, 0, 16, stream);         // ws re-poisoned 0xAA each call
    sce_main<<<NBLK, TPB, 0, stream>>>(sim, gt, accf, ticket, (float*)d_out);
}

// Round 4
// 501.117 us; speedup vs baseline: 1.0681x; 1.0681x over previous
//
#include <hip/hip_runtime.h>
#include <math.h>

// Problem shape (fixed by setup_inputs)
constexpr int Bn = 8, Dn = 64, Hn = 256, Wn = 512;
constexpr int HW    = Hn * Wn;            // 131072
constexpr int NPIX  = Bn * HW;            // 1048576
constexpr int TPB   = 256;
constexpr int PPT   = 4;                  // pixels per thread (one float4)
constexpr int NBLK  = NPIX / (TPB * PPT); // 1024
constexpr int BATCH = 16;                 // d-planes per pipeline stage
constexpr int NB    = Dn / BATCH;         // 4 stages

typedef float fx4 __attribute__((ext_vector_type(4)));

// entropy(p) = log(sum_d exp(sim_d)) - (sum_d T_d*sim_d)/(sum_d T_d),
// T_d = exp(-|g-2d|) = min( e^{g-64} * e^{-2(d-32)},  e^{64-g} * e^{2(d-32)} ).
// Center d=32: exponents of the literals are in [-64,62] -> all finite fp32.
// g=inf (unknown): Pa=inf, Pb=0 -> t=min(inf*ra, 0*rb)=min(inf,0)=0, no NaN.
__global__ __launch_bounds__(TPB, 2) void sce_main(const float* __restrict__ sim,
                                                   const float* __restrict__ gt,
                                                   float* __restrict__ accf,
                                                   unsigned* __restrict__ ticket,
                                                   float* __restrict__ out) {
    const int tid = blockIdx.x * TPB + threadIdx.x;
    const int p0  = tid * PPT;
    const int b   = p0 / HW;
    const int rem = p0 - b * HW;
    const float* base = sim + (size_t)b * Dn * HW + rem;

    const fx4 g4 = *reinterpret_cast<const fx4*>(gt + p0);
    float gg[4] = {g4.x, g4.y, g4.z, g4.w};

    float Pa[4], Pb[4];
#pragma unroll
    for (int j = 0; j < 4; ++j) {
        Pa[j] = __expf(gg[j] - 64.0f);   // e^{g-64}  (inf for unknown, ok)
        Pb[j] = __expf(64.0f - gg[j]);   // e^{64-g}  (0 for unknown, ok)
    }

    float s[4]  = {0.f, 0.f, 0.f, 0.f};  // sum exp(sim)
    float S1[4] = {0.f, 0.f, 0.f, 0.f};  // sum T
    float S2[4] = {0.f, 0.f, 0.f, 0.f};  // sum T*sim

    // 16-deep double-buffered pipeline: 32 KiB per wave in flight.
    fx4 cur[BATCH], nxt[BATCH];
#pragma unroll
    for (int i = 0; i < BATCH; ++i)
        cur[i] = *reinterpret_cast<const fx4*>(base + (size_t)i * HW);

#pragma unroll
    for (int g = 0; g < NB; ++g) {
        if (g + 1 < NB) {
#pragma unroll
            for (int i = 0; i < BATCH; ++i)
                nxt[i] = *reinterpret_cast<const fx4*>(
                    base + (size_t)((g + 1) * BATCH + i) * HW);
        }
#pragma unroll
        for (int i = 0; i < BATCH; ++i) {
            const int d = g * BATCH + i;
            const float ra = __builtin_expf(-2.0f * (float)(d - 32)); // literal
            const float rb = __builtin_expf( 2.0f * (float)(d - 32)); // literal
            float v[4] = {cur[i].x, cur[i].y, cur[i].z, cur[i].w};
#pragma unroll
            for (int j = 0; j < 4; ++j) {
                s[j] += __expf(v[j]);
                float t = fminf(Pa[j] * ra, Pb[j] * rb);  // exp(-|g-2d|)
                S1[j] += t;
                S2[j] = fmaf(t, v[j], S2[j]);
            }
        }
#pragma unroll
        for (int i = 0; i < BATCH; ++i) cur[i] = nxt[i];
    }

    float lsum = 0.0f, lcnt = 0.0f;
#pragma unroll
    for (int j = 0; j < 4; ++j) {
        if (isfinite(gg[j])) {           // unknown gt excluded
            lsum += __logf(s[j]) - S2[j] / S1[j];
            lcnt += 1.0f;
        }
    }

    // 64-lane wave reduction
#pragma unroll
    for (int off = 32; off > 0; off >>= 1) {
        lsum += __shfl_down(lsum, off, 64);
        lcnt += __shfl_down(lcnt, off, 64);
    }

    __shared__ float ssum[TPB / 64], scnt[TPB / 64];
    const int lane = threadIdx.x & 63;
    const int wave = threadIdx.x >> 6;
    if (lane == 0) { ssum[wave] = lsum; scnt[wave] = lcnt; }
    __syncthreads();
    if (threadIdx.x == 0) {
        float bs = 0.f, bc = 0.f;
#pragma unroll
        for (int w = 0; w < TPB / 64; ++w) { bs += ssum[w]; bc += scnt[w]; }
        atomicAdd(&accf[0], bs);
        atomicAdd(&accf[1], bc);
        __threadfence();
        unsigned old = atomicAdd(ticket, 1u);
        if (old == NBLK - 1) {           // last block finalizes in-kernel
            __threadfence();
            float ts = atomicAdd(&accf[0], 0.0f);
            float tc = atomicAdd(&accf[1], 0.0f);
            out[0] = ts / tc;
        }
    }
}

extern "C" void kernel_launch(void* const* d_in, const int* in_sizes, int n_in,
                              void* d_out, int out_size, void* d_ws, size_t ws_size,
                              hipStream_t stream) {
    const float* sim = (const float*)d_in[0];
    const float* gt  = (const float*)d_in[1];
    float* accf = (float*)d_ws;                  // [sum, cnt]
    unsigned* ticket = (unsigned*)d_ws + 2;
    hipMemsetAsync(d_ws, 0, 16, stream);         // ws re-poisoned 0xAA each call
    sce_main<<<NBLK, TPB, 0, stream>>>(sim, gt, accf, ticket, (float*)d_out);
}

// Round 5
// 471.367 us; speedup vs baseline: 1.1355x; 1.0631x over previous
//
#include <hip/hip_runtime.h>
#include <math.h>

// Problem shape (fixed by setup_inputs)
constexpr int Bn = 8, Dn = 64, Hn = 256, Wn = 512;
constexpr int HW   = Hn * Wn;            // 131072
constexpr int NPIX = Bn * HW;            // 1048576
constexpr int TPB  = 256;                // 4 waves
constexpr int NW   = TPB / 64;           // waves per block
constexpr int PXW  = 256;                // pixels per wave (64 lanes x float4)
constexpr int PXB  = NW * PXW;           // 1024 pixels per block
constexpr int NBLK = NPIX / PXB;         // 1024 blocks (all co-resident)
constexpr int CP   = 4;                  // d-planes per chunk
constexpr int NC   = Dn / CP;            // 16 chunks

typedef float fx4 __attribute__((ext_vector_type(4)));

// Async global->LDS DMA, 16B per lane. LDS dest is wave-uniform base + lane*16
// (hardware takes firstlane of lptr); gptr is per-lane. Zero VGPR cost.
__device__ inline void load_lds16(const float* g, float* l) {
    __builtin_amdgcn_global_load_lds(
        (const __attribute__((address_space(1))) void*)g,
        (__attribute__((address_space(3))) void*)l, 16, 0, 0);
}

// entropy(p) = log(sum_d exp(sim_d)) - (sum_d T_d*sim_d)/(sum_d T_d),
// T_d = exp(-|g-2d|) = min( e^{g-64}*e^{-2(d-32)}, e^{64-g}*e^{2(d-32)} ).
// All intermediates finite or flush identically to the fp32 reference;
// g=inf (unknown): Pa=inf, Pb=0 -> t=min(inf,0)=0, no NaN; pixel excluded.
__global__ __launch_bounds__(TPB) void sce_main(const float* __restrict__ sim,
                                                const float* __restrict__ gt,
                                                float* __restrict__ accf,
                                                unsigned* __restrict__ ticket,
                                                float* __restrict__ out) {
    __shared__ float stage[NW][2][CP][PXW];   // 32 KiB: per-wave private dbuf

    const int lane = threadIdx.x & 63;
    const int wave = threadIdx.x >> 6;
    const int p0   = blockIdx.x * PXB + wave * PXW + lane * 4;  // tile never crosses image
    const int b    = p0 / HW;
    const int rem  = p0 - b * HW;
    const float* gbase = sim + (size_t)b * Dn * HW + rem;       // + lane*4 already in rem? no:
    // rem includes lane*4 (p0 has it), so gbase is already the per-lane address.

    // Consume gt BEFORE any DMA is issued so its vmcnt wait can't stall the pipe.
    const fx4 g4 = *reinterpret_cast<const fx4*>(gt + p0);
    float gg[4] = {g4.x, g4.y, g4.z, g4.w};
    float Pa[4], Pb[4];
#pragma unroll
    for (int j = 0; j < 4; ++j) {
        Pa[j] = __expf(gg[j] - 64.0f);   // e^{g-64}  (inf for unknown: ok)
        Pb[j] = __expf(64.0f - gg[j]);   // e^{64-g}  (0 for unknown: ok)
    }
    asm volatile("" ::: "memory");       // keep gt-use ordered before DMA issue

    auto issue_chunk = [&](int c, int buf) {
#pragma unroll
        for (int i = 0; i < CP; ++i)
            load_lds16(gbase + (size_t)(c * CP + i) * HW, &stage[wave][buf][i][0]);
    };

    issue_chunk(0, 0);                   // 2-deep pipeline, 8 KiB/wave in flight
    issue_chunk(1, 1);

    float s[4]  = {0.f, 0.f, 0.f, 0.f};
    float S1[4] = {0.f, 0.f, 0.f, 0.f};
    float S2[4] = {0.f, 0.f, 0.f, 0.f};

#pragma unroll
    for (int c = 0; c < NC; ++c) {
        if (c < NC - 1) asm volatile("s_waitcnt vmcnt(4)" ::: "memory");  // chunk c landed
        else            asm volatile("s_waitcnt vmcnt(0)" ::: "memory");
        const int buf = c & 1;
#pragma unroll
        for (int i = 0; i < CP; ++i) {
            const int d = c * CP + i;
            const float ra = __builtin_expf(-2.0f * (float)(d - 32));  // folded literal
            const float rb = __builtin_expf( 2.0f * (float)(d - 32));  // folded literal
            fx4 vv = *reinterpret_cast<const fx4*>(&stage[wave][buf][i][lane * 4]);
            float v[4] = {vv.x, vv.y, vv.z, vv.w};
#pragma unroll
            for (int j = 0; j < 4; ++j) {
                s[j] += __expf(v[j]);
                float t = fminf(Pa[j] * ra, Pb[j] * rb);  // exp(-|g-2d|)
                S1[j] += t;
                S2[j] = fmaf(t, v[j], S2[j]);
            }
        }
        if (c + 2 < NC) {
            // ds_reads of this buffer are in VGPRs once lgkmcnt drains; then reuse it.
            asm volatile("s_waitcnt lgkmcnt(0)" ::: "memory");
            issue_chunk(c + 2, buf);
        }
    }

    float lsum = 0.0f, lcnt = 0.0f;
#pragma unroll
    for (int j = 0; j < 4; ++j) {
        if (isfinite(gg[j])) {           // unknown gt excluded
            lsum += __logf(s[j]) - S2[j] / S1[j];
            lcnt += 1.0f;
        }
    }

    // 64-lane wave reduction; one atomic pair per wave (4096 total, negligible).
#pragma unroll
    for (int off = 32; off > 0; off >>= 1) {
        lsum += __shfl_down(lsum, off, 64);
        lcnt += __shfl_down(lcnt, off, 64);
    }
    if (lane == 0) {
        atomicAdd(&accf[0], lsum);       // device-scope by default
        atomicAdd(&accf[1], lcnt);
        __threadfence();
        unsigned old = atomicAdd(ticket, 1u);
        if (old == NBLK * NW - 1) {      // last wave finalizes in-kernel
            __threadfence();
            float ts = atomicAdd(&accf[0], 0.0f);
            float tc = atomicAdd(&accf[1], 0.0f);
            out[0] = ts / tc;
        }
    }
}

extern "C" void kernel_launch(void* const* d_in, const int* in_sizes, int n_in,
                              void* d_out, int out_size, void* d_ws, size_t ws_size,
                              hipStream_t stream) {
    const float* sim = (const float*)d_in[0];
    const float* gt  = (const float*)d_in[1];
    float* accf = (float*)d_ws;                  // [sum, cnt]
    unsigned* ticket = (unsigned*)d_ws + 2;
    hipMemsetAsync(d_ws, 0, 16, stream);         // ws re-poisoned 0xAA each call
    sce_main<<<NBLK, TPB, 0, stream>>>(sim, gt, accf, ticket, (float*)d_out);
}